// Round 3
// baseline (176.451 us; speedup 1.0000x reference)
//
#include <hip/hip_runtime.h>
#include <hip/hip_bf16.h>
#include <stdint.h>

#define BB 32
#define IC 128
#define OC 128
#define HH 56
#define WW 56
#define ZD 512
#define NRS 9
#define OI (OC*IC)            // 16384
#define WROWS (OI*NRS)        // 147456
#define WDIM 58               // padded LDS width index u = w_in+1, 0..57

typedef float  f32x4  __attribute__((ext_vector_type(4)));
typedef short  bf16x8 __attribute__((ext_vector_type(8)));

static __device__ __forceinline__ short f2bf(float f) {
    uint32_t u = __float_as_uint(f);
    uint32_t r = (u + 0x7fffu + ((u >> 16) & 1u)) >> 16;
    return (short)r;
}
static __device__ __forceinline__ short f2bf_hw(float f) {
    __hip_bfloat16 h = __float2bfloat16(f);
    return *reinterpret_cast<short*>(&h);
}

// ---------------------------------------------------------------------------
// Kernel 1 (v3): hypernet head via MFMA + global_load_lds streaming of Wh.
// Block: 256 thr = 4 waves, owns 128 Wh rows x all 32 b.  K-steps of 32 floats.
// Wl: double-buffered [128 rows][128 B] fp32 tile, XOR-swizzled (row%8)<<4 via
// pre-swizzled SOURCE address (linear LDS dest, rule #21).  Zl: z bf16,
// swizzled (b&7)<<4.  2-phase loop: STAGE(next); compute(cur); __syncthreads.
// mfma(A=z, B=Wh_rows): D col = Wh-row (lane&15), D row = b (4*(lane>>4)+reg).
// ---------------------------------------------------------------------------
__global__ __launch_bounds__(256) void head_kernel(
    const float* __restrict__ Wh, const float* __restrict__ z,
    const float* __restrict__ bh, short* __restrict__ wout)
{
    __shared__ __align__(16) char Zl[32 * 1024];   // 32 KB z bf16 swizzled
    __shared__ __align__(16) char Wl[2 * 16384];   // 2 x 16 KB fp32 W tiles
    const int tid  = threadIdx.x;
    const int lane = tid & 63;
    const int wv   = tid >> 6;

    // stage z once: thread t -> b = t>>3, k-range (t&7)*64..+63, swz ^((b&7)<<4)
    {
        const int b = tid >> 3, ks = (tid & 7) * 64;
        const float* zp = z + (size_t)b * ZD + ks;
        const int bx = (b & 7) << 4;
        #pragma unroll
        for (int j8 = 0; j8 < 8; ++j8) {
            f32x4 v0 = *(const f32x4*)(zp + j8 * 8);
            f32x4 v1 = *(const f32x4*)(zp + j8 * 8 + 4);
            bf16x8 pk;
            pk[0] = f2bf_hw(v0.x); pk[1] = f2bf_hw(v0.y);
            pk[2] = f2bf_hw(v0.z); pk[3] = f2bf_hw(v0.w);
            pk[4] = f2bf_hw(v1.x); pk[5] = f2bf_hw(v1.y);
            pk[6] = f2bf_hw(v1.z); pk[7] = f2bf_hw(v1.w);
            *(bf16x8*)(Zl + b * 1024 + ((ks * 2 + j8 * 16) ^ bx)) = pk;
        }
    }

    // W staging geometry: round r (0..3): wave writes 1 KB at
    //   Wl + buf*16384 + r*4096 + wv*1024, lane scatter = +lane*16 (implicit).
    // LDS (row, cbyte) = (r*32 + wv*8 + (lane>>3), (lane&7)*16); swizzle
    // row%8 = lane>>3, so source byte = c ^ ((lane>>3)<<4).
    const int lrow = wv * 8 + (lane >> 3);               // row base within round-chunk
    const char* wsrc0 = (const char*)Wh
        + ((size_t)(blockIdx.x * 128 + lrow)) * (ZD * 4)
        + (((lane & 7) * 16) ^ (((lane >> 3) & 7) << 4));

    #define STAGE_W(buf, kb)                                                     \
        _Pragma("unroll")                                                        \
        for (int rnd = 0; rnd < 4; ++rnd) {                                      \
            __builtin_amdgcn_global_load_lds(                                    \
                (const __attribute__((address_space(1))) uint32_t*)              \
                    (wsrc0 + (size_t)rnd * 32 * (ZD * 4) + (kb) * 128),          \
                (__attribute__((address_space(3))) uint32_t*)                    \
                    (Wl + (buf) * 16384 + rnd * 4096 + wv * 1024),               \
                16, 0, 0);                                                       \
        }

    STAGE_W(0, 0);
    __syncthreads();   // drains z ds_writes + kb=0 stage

    const int rl = lane & 15;      // = local W-row in frag = D col; = b in A frag
    const int kq = lane >> 4;
    const int zxor = (rl & 7) << 4;

    f32x4 acc[2][2];
    #pragma unroll
    for (int rf = 0; rf < 2; ++rf)
        #pragma unroll
        for (int bt = 0; bt < 2; ++bt) acc[rf][bt] = (f32x4){0.f, 0.f, 0.f, 0.f};

    for (int kb = 0; kb < 16; ++kb) {
        const int cur = kb & 1;
        if (kb < 15) STAGE_W(cur ^ 1, kb + 1);

        const int koff = (kb * 64 + kq * 16) ^ zxor;
        bf16x8 a0 = *(const bf16x8*)(Zl + rl * 1024 + koff);
        bf16x8 a1 = *(const bf16x8*)(Zl + (16 + rl) * 1024 + koff);

        #pragma unroll
        for (int rf = 0; rf < 2; ++rf) {
            const int r = (2 * wv + rf) * 16 + rl;       // row in tile; r%8 == rl%8
            const char* wb = Wl + cur * 16384 + r * 128;
            f32x4 lo = *(const f32x4*)(wb + ((kq * 32) ^ zxor));
            f32x4 hi = *(const f32x4*)(wb + ((kq * 32 + 16) ^ zxor));
            bf16x8 bw;
            bw[0] = f2bf_hw(lo.x); bw[1] = f2bf_hw(lo.y);
            bw[2] = f2bf_hw(lo.z); bw[3] = f2bf_hw(lo.w);
            bw[4] = f2bf_hw(hi.x); bw[5] = f2bf_hw(hi.y);
            bw[6] = f2bf_hw(hi.z); bw[7] = f2bf_hw(hi.w);
            acc[rf][0] = __builtin_amdgcn_mfma_f32_16x16x32_bf16(a0, bw, acc[rf][0], 0, 0, 0);
            acc[rf][1] = __builtin_amdgcn_mfma_f32_16x16x32_bf16(a1, bw, acc[rf][1], 0, 0, 0);
        }
        __syncthreads();   // drain next-tile stage (vmcnt) + protect buffers
    }

    // D: col = lane&15 (= W row), row = 4*kq+reg (= batch b)
    #pragma unroll
    for (int rf = 0; rf < 2; ++rf) {
        const int rowg = blockIdx.x * 128 + (2 * wv + rf) * 16 + rl;
        const float bias = bh[rowg];
        const int oi = rowg / 9, rs = rowg - oi * 9;
        const size_t outb = (size_t)rs * OI + oi;
        #pragma unroll
        for (int reg = 0; reg < 4; ++reg) {
            const int b0 = kq * 4 + reg;
            wout[(size_t)b0 * WROWS + outb]        = f2bf(acc[rf][0][reg] + bias);
            wout[(size_t)(16 + b0) * WROWS + outb] = f2bf(acc[rf][1][reg] + bias);
        }
    }
    #undef STAGE_W
}

// ---------------------------------------------------------------------------
// Kernel 2: x [b][i][h][w] fp32  ->  xt [b][h][w][i] bf16
// ---------------------------------------------------------------------------
__global__ __launch_bounds__(256) void transpose_kernel(
    const float* __restrict__ x, short* __restrict__ xt)
{
    const int h = blockIdx.x;          // 56
    const int b = blockIdx.y;          // 32
    const int w = threadIdx.x & 63;
    const int yq = threadIdx.x >> 6;   // 0..3
    if (w >= WW) return;
    const float* xp = x + (size_t)b * IC * HH * WW + h * WW + w;
    short* op = xt + (((size_t)(b * HH + h)) * WW + w) * IC;
    #pragma unroll
    for (int q = 0; q < 4; ++q) {
        int ic = yq * 4 + q;           // 0..15
        bf16x8 pk;
        #pragma unroll
        for (int j = 0; j < 8; ++j) {
            float v = xp[(size_t)(ic * 8 + j) * (HH * WW)];
            pk[j] = f2bf(v);
        }
        *(bf16x8*)(op + ic * 8) = pk;
    }
}

// ---------------------------------------------------------------------------
// Kernel 3: per-sample conv as 9 shifted GEMMs with bf16 MFMA (unchanged).
// ---------------------------------------------------------------------------
__global__ __launch_bounds__(256) void conv_kernel(
    const short* __restrict__ wbf,   // [b][rs][o][i] bf16
    const short* __restrict__ xt,    // [b][h][w][i]  bf16
    float* __restrict__ out)         // [b][o][h][w]  fp32
{
    __shared__ __align__(16) char Xl[3 * WDIM * 256];  // 44544 B
    __shared__ __align__(16) char Wl[128 * 256];       // 32768 B
    const int tid  = threadIdx.x;
    const int lane = tid & 63;
    const int wv   = tid >> 6;       // wave 0..3
    const int h = blockIdx.x;        // 56
    const int b = blockIdx.y;        // 32

    #pragma unroll
    for (int q = 0; q < 11; ++q) {
        int idx = tid + q * 256;
        if (idx < 3 * WDIM * 16) ((f32x4*)Xl)[idx] = (f32x4){0.f, 0.f, 0.f, 0.f};
    }
    __syncthreads();

    for (int r = 0; r < 3; ++r) {
        int hin = h + r - 1;
        if (hin < 0 || hin >= HH) continue;
        const char* src = (const char*)(xt + ((size_t)(b * HH + hin)) * WW * IC);
        char* dstbase = Xl + (r * WDIM + 1) * 256;
        for (int it = wv; it < 14; it += 4) {
            int c = it * 64 + lane;
            int u = r * WDIM + 1 + (c >> 4);
            int soff = (c * 16) ^ ((u & 7) << 4);
            __builtin_amdgcn_global_load_lds(
                (const __attribute__((address_space(1))) uint32_t*)(src + soff),
                (__attribute__((address_space(3))) uint32_t*)(dstbase + it * 1024),
                16, 0, 0);
        }
    }

    f32x4 acc[2][4];
    #pragma unroll
    for (int a = 0; a < 2; ++a)
        #pragma unroll
        for (int p = 0; p < 4; ++p) acc[a][p] = (f32x4){0.f, 0.f, 0.f, 0.f};

    const int axor = (lane & 7) << 4;
    int kkoff[4];
    #pragma unroll
    for (int kk = 0; kk < 4; ++kk) kkoff[kk] = kk * 64 + ((lane >> 4) << 4);

    for (int rs = 0; rs < 9; ++rs) {
        __syncthreads();
        const char* wsrc = (const char*)(wbf + ((size_t)b * NRS + rs) * OI);
        for (int it = wv; it < 32; it += 4) {
            int c = it * 64 + lane;
            int soff = (c * 16) ^ (((c >> 4) & 7) << 4);
            __builtin_amdgcn_global_load_lds(
                (const __attribute__((address_space(1))) uint32_t*)(wsrc + soff),
                (__attribute__((address_space(3))) uint32_t*)(Wl + it * 1024),
                16, 0, 0);
        }
        __syncthreads();

        const int r = rs / 3, s = rs - 3 * (rs / 3);
        int ubase[4], bswz[4];
        #pragma unroll
        for (int pf = 0; pf < 4; ++pf) {
            int p = pf * 16 + (lane & 15);
            int pc = p > 55 ? 55 : p;
            int uu = r * WDIM + pc + s;
            ubase[pf] = uu * 256;
            bswz[pf] = (uu & 7) << 4;
        }
        #pragma unroll
        for (int kk = 0; kk < 4; ++kk) {
            bf16x8 a0 = *(const bf16x8*)(Wl + (wv * 32 + (lane & 15)) * 256 +
                                         (kkoff[kk] ^ axor));
            bf16x8 a1 = *(const bf16x8*)(Wl + (wv * 32 + 16 + (lane & 15)) * 256 +
                                         (kkoff[kk] ^ axor));
            #pragma unroll
            for (int pf = 0; pf < 4; ++pf) {
                bf16x8 bv = *(const bf16x8*)(Xl + ubase[pf] + (kkoff[kk] ^ bswz[pf]));
                acc[0][pf] = __builtin_amdgcn_mfma_f32_16x16x32_bf16(a0, bv, acc[0][pf], 0, 0, 0);
                acc[1][pf] = __builtin_amdgcn_mfma_f32_16x16x32_bf16(a1, bv, acc[1][pf], 0, 0, 0);
            }
        }
    }

    const int pcol = lane & 15;
    const int rowq = lane >> 4;
    #pragma unroll
    for (int a = 0; a < 2; ++a) {
        int o0 = wv * 32 + a * 16 + rowq * 4;
        #pragma unroll
        for (int pf = 0; pf < 4; ++pf) {
            int p = pf * 16 + pcol;
            if (p < WW) {
                #pragma unroll
                for (int reg = 0; reg < 4; ++reg) {
                    out[(((size_t)b * OC + (o0 + reg)) * HH + h) * WW + p] = acc[a][pf][reg];
                }
            }
        }
    }
}

extern "C" void kernel_launch(void* const* d_in, const int* in_sizes, int n_in,
                              void* d_out, int out_size, void* d_ws, size_t ws_size,
                              hipStream_t stream) {
    const float* x  = (const float*)d_in[0];   // [32,128,56,56]
    const float* z  = (const float*)d_in[1];   // [32,512]
    const float* Wh = (const float*)d_in[2];   // [147456,512]
    const float* bh = (const float*)d_in[3];   // [147456]
    float* out = (float*)d_out;

    short* wbf = (short*)d_ws;                               // 9,437,184 B
    short* xt  = (short*)((char*)d_ws + (size_t)BB * NRS * OI * 2);  // +25,690,112 B

    head_kernel<<<dim3(WROWS / 128), 256, 0, stream>>>(Wh, z, bh, wbf);
    transpose_kernel<<<dim3(HH, BB), 256, 0, stream>>>(x, xt);
    conv_kernel<<<dim3(HH, BB), 256, 0, stream>>>(wbf, xt, out);
}

// Round 4
// 174.887 us; speedup vs baseline: 1.0089x; 1.0089x over previous
//
#include <hip/hip_runtime.h>
#include <hip/hip_bf16.h>
#include <stdint.h>

#define BB 32
#define IC 128
#define OC 128
#define HH 56
#define WW 56
#define ZD 512
#define NRS 9
#define OI (OC*IC)            // 16384
#define WROWS (OI*NRS)        // 147456
#define WDIM 58               // padded LDS width index u = w_in+1, 0..57

typedef float  f32x4  __attribute__((ext_vector_type(4)));
typedef short  bf16x8 __attribute__((ext_vector_type(8)));

static __device__ __forceinline__ short f2bf(float f) {
    uint32_t u = __float_as_uint(f);
    uint32_t r = (u + 0x7fffu + ((u >> 16) & 1u)) >> 16;
    return (short)r;
}
static __device__ __forceinline__ short f2bf_hw(float f) {
    __hip_bfloat16 h = __float2bfloat16(f);
    return *reinterpret_cast<short*>(&h);
}

// ---------------------------------------------------------------------------
// Kernel 1 (v4): head with T4 counted-vmcnt pipeline.
// 3 W-buffers (16 KB each), 2-ahead prefetch, s_waitcnt vmcnt(4) + one
// s_barrier per K-step — never drain to 0 in the main loop (m218 lever).
// Wave-symmetric vmcnt: every wave issues exactly 4 global_load_lds per group.
// Buffer reuse distance 3: write slot (kb+2)%3 == read slot of kb-1, ordered
// by the barrier (all waves' kb-1 ds_reads complete before their barrier
// arrival; stage data lands after).  LDS: Zl 32K + Wl 48K = 80K -> 2 blk/CU.
// ---------------------------------------------------------------------------
__global__ __launch_bounds__(256) void head_kernel(
    const float* __restrict__ Wh, const float* __restrict__ z,
    const float* __restrict__ bh, short* __restrict__ wout)
{
    __shared__ __align__(16) char Zl[32 * 1024];   // z bf16 swizzled
    __shared__ __align__(16) char Wl[3 * 16384];   // 3 x 16 KB fp32 W tiles
    const int tid  = threadIdx.x;
    const int lane = tid & 63;
    const int wv   = tid >> 6;

    // stage z once: thread t -> b = t>>3, k-range (t&7)*64..+63, swz ^((b&7)<<4)
    {
        const int b = tid >> 3, ks = (tid & 7) * 64;
        const float* zp = z + (size_t)b * ZD + ks;
        const int bx = (b & 7) << 4;
        #pragma unroll
        for (int j8 = 0; j8 < 8; ++j8) {
            f32x4 v0 = *(const f32x4*)(zp + j8 * 8);
            f32x4 v1 = *(const f32x4*)(zp + j8 * 8 + 4);
            bf16x8 pk;
            pk[0] = f2bf_hw(v0.x); pk[1] = f2bf_hw(v0.y);
            pk[2] = f2bf_hw(v0.z); pk[3] = f2bf_hw(v0.w);
            pk[4] = f2bf_hw(v1.x); pk[5] = f2bf_hw(v1.y);
            pk[6] = f2bf_hw(v1.z); pk[7] = f2bf_hw(v1.w);
            *(bf16x8*)(Zl + b * 1024 + ((ks * 2 + j8 * 16) ^ bx)) = pk;
        }
    }
    __syncthreads();   // z ready (full drain, before any W prefetch)

    // W staging: wave writes rounds 0..3, 1 KB each, linear LDS dest;
    // source pre-swizzled so LDS (row, c) = (..., c ^ ((row&7)<<4)).
    const int lrow = wv * 8 + (lane >> 3);
    const char* wsrc0 = (const char*)Wh
        + ((size_t)(blockIdx.x * 128 + lrow)) * (ZD * 4)
        + (((lane & 7) * 16) ^ (((lane >> 3) & 7) << 4));

    #define STAGE_W(slot, kb)                                                    \
        _Pragma("unroll")                                                        \
        for (int rnd = 0; rnd < 4; ++rnd) {                                      \
            __builtin_amdgcn_global_load_lds(                                    \
                (const __attribute__((address_space(1))) uint32_t*)              \
                    (wsrc0 + (size_t)rnd * 32 * (ZD * 4) + (size_t)(kb) * 128),  \
                (__attribute__((address_space(3))) uint32_t*)                    \
                    (Wl + (slot) * 16384 + rnd * 4096 + wv * 1024),              \
                16, 0, 0);                                                       \
        }

    STAGE_W(0, 0);
    STAGE_W(1, 1);

    const int rl = lane & 15;      // W-row in frag (D col); b in A frag
    const int kq = lane >> 4;
    const int zxor = (rl & 7) << 4;

    f32x4 acc[2][2];
    #pragma unroll
    for (int rf = 0; rf < 2; ++rf)
        #pragma unroll
        for (int bt = 0; bt < 2; ++bt) acc[rf][bt] = (f32x4){0.f, 0.f, 0.f, 0.f};

    #pragma unroll
    for (int kb = 0; kb < 16; ++kb) {
        if (kb == 15) asm volatile("s_waitcnt vmcnt(0)" ::: "memory");
        else          asm volatile("s_waitcnt vmcnt(4)" ::: "memory");
        __builtin_amdgcn_sched_barrier(0);
        __builtin_amdgcn_s_barrier();
        __builtin_amdgcn_sched_barrier(0);
        if (kb + 2 < 16) { STAGE_W((kb + 2) % 3, kb + 2); }

        const int slot = kb % 3;
        const int koff = (kb * 64 + kq * 16) ^ zxor;
        bf16x8 a0 = *(const bf16x8*)(Zl + rl * 1024 + koff);
        bf16x8 a1 = *(const bf16x8*)(Zl + (16 + rl) * 1024 + koff);

        #pragma unroll
        for (int rf = 0; rf < 2; ++rf) {
            const int r = (2 * wv + rf) * 16 + rl;       // r%8 == rl%8
            const char* wb = Wl + slot * 16384 + r * 128;
            f32x4 lo = *(const f32x4*)(wb + ((kq * 32) ^ zxor));
            f32x4 hi = *(const f32x4*)(wb + ((kq * 32 + 16) ^ zxor));
            bf16x8 bw;
            bw[0] = f2bf_hw(lo.x); bw[1] = f2bf_hw(lo.y);
            bw[2] = f2bf_hw(lo.z); bw[3] = f2bf_hw(lo.w);
            bw[4] = f2bf_hw(hi.x); bw[5] = f2bf_hw(hi.y);
            bw[6] = f2bf_hw(hi.z); bw[7] = f2bf_hw(hi.w);
            acc[rf][0] = __builtin_amdgcn_mfma_f32_16x16x32_bf16(a0, bw, acc[rf][0], 0, 0, 0);
            acc[rf][1] = __builtin_amdgcn_mfma_f32_16x16x32_bf16(a1, bw, acc[rf][1], 0, 0, 0);
        }
    }
    #undef STAGE_W

    // D: col = lane&15 (= W row), row = 4*kq+reg (= batch b)
    #pragma unroll
    for (int rf = 0; rf < 2; ++rf) {
        const int rowg = blockIdx.x * 128 + (2 * wv + rf) * 16 + rl;
        const float bias = bh[rowg];
        const int oi = rowg / 9, rs = rowg - oi * 9;
        const size_t outb = (size_t)rs * OI + oi;
        #pragma unroll
        for (int reg = 0; reg < 4; ++reg) {
            const int b0 = kq * 4 + reg;
            wout[(size_t)b0 * WROWS + outb]        = f2bf(acc[rf][0][reg] + bias);
            wout[(size_t)(16 + b0) * WROWS + outb] = f2bf(acc[rf][1][reg] + bias);
        }
    }
}

// ---------------------------------------------------------------------------
// Kernel 2: x [b][i][h][w] fp32  ->  xt [b][h][w][i] bf16
// ---------------------------------------------------------------------------
__global__ __launch_bounds__(256) void transpose_kernel(
    const float* __restrict__ x, short* __restrict__ xt)
{
    const int h = blockIdx.x;          // 56
    const int b = blockIdx.y;          // 32
    const int w = threadIdx.x & 63;
    const int yq = threadIdx.x >> 6;   // 0..3
    if (w >= WW) return;
    const float* xp = x + (size_t)b * IC * HH * WW + h * WW + w;
    short* op = xt + (((size_t)(b * HH + h)) * WW + w) * IC;
    #pragma unroll
    for (int q = 0; q < 4; ++q) {
        int ic = yq * 4 + q;           // 0..15
        bf16x8 pk;
        #pragma unroll
        for (int j = 0; j < 8; ++j) {
            float v = xp[(size_t)(ic * 8 + j) * (HH * WW)];
            pk[j] = f2bf(v);
        }
        *(bf16x8*)(op + ic * 8) = pk;
    }
}

// ---------------------------------------------------------------------------
// Kernel 3: per-sample conv as 9 shifted GEMMs with bf16 MFMA (unchanged).
// ---------------------------------------------------------------------------
__global__ __launch_bounds__(256) void conv_kernel(
    const short* __restrict__ wbf,   // [b][rs][o][i] bf16
    const short* __restrict__ xt,    // [b][h][w][i]  bf16
    float* __restrict__ out)         // [b][o][h][w]  fp32
{
    __shared__ __align__(16) char Xl[3 * WDIM * 256];  // 44544 B
    __shared__ __align__(16) char Wl[128 * 256];       // 32768 B
    const int tid  = threadIdx.x;
    const int lane = tid & 63;
    const int wv   = tid >> 6;       // wave 0..3
    const int h = blockIdx.x;        // 56
    const int b = blockIdx.y;        // 32

    #pragma unroll
    for (int q = 0; q < 11; ++q) {
        int idx = tid + q * 256;
        if (idx < 3 * WDIM * 16) ((f32x4*)Xl)[idx] = (f32x4){0.f, 0.f, 0.f, 0.f};
    }
    __syncthreads();

    for (int r = 0; r < 3; ++r) {
        int hin = h + r - 1;
        if (hin < 0 || hin >= HH) continue;
        const char* src = (const char*)(xt + ((size_t)(b * HH + hin)) * WW * IC);
        char* dstbase = Xl + (r * WDIM + 1) * 256;
        for (int it = wv; it < 14; it += 4) {
            int c = it * 64 + lane;
            int u = r * WDIM + 1 + (c >> 4);
            int soff = (c * 16) ^ ((u & 7) << 4);
            __builtin_amdgcn_global_load_lds(
                (const __attribute__((address_space(1))) uint32_t*)(src + soff),
                (__attribute__((address_space(3))) uint32_t*)(dstbase + it * 1024),
                16, 0, 0);
        }
    }

    f32x4 acc[2][4];
    #pragma unroll
    for (int a = 0; a < 2; ++a)
        #pragma unroll
        for (int p = 0; p < 4; ++p) acc[a][p] = (f32x4){0.f, 0.f, 0.f, 0.f};

    const int axor = (lane & 7) << 4;
    int kkoff[4];
    #pragma unroll
    for (int kk = 0; kk < 4; ++kk) kkoff[kk] = kk * 64 + ((lane >> 4) << 4);

    for (int rs = 0; rs < 9; ++rs) {
        __syncthreads();
        const char* wsrc = (const char*)(wbf + ((size_t)b * NRS + rs) * OI);
        for (int it = wv; it < 32; it += 4) {
            int c = it * 64 + lane;
            int soff = (c * 16) ^ (((c >> 4) & 7) << 4);
            __builtin_amdgcn_global_load_lds(
                (const __attribute__((address_space(1))) uint32_t*)(wsrc + soff),
                (__attribute__((address_space(3))) uint32_t*)(Wl + it * 1024),
                16, 0, 0);
        }
        __syncthreads();

        const int r = rs / 3, s = rs - 3 * (rs / 3);
        int ubase[4], bswz[4];
        #pragma unroll
        for (int pf = 0; pf < 4; ++pf) {
            int p = pf * 16 + (lane & 15);
            int pc = p > 55 ? 55 : p;
            int uu = r * WDIM + pc + s;
            ubase[pf] = uu * 256;
            bswz[pf] = (uu & 7) << 4;
        }
        #pragma unroll
        for (int kk = 0; kk < 4; ++kk) {
            bf16x8 a0 = *(const bf16x8*)(Wl + (wv * 32 + (lane & 15)) * 256 +
                                         (kkoff[kk] ^ axor));
            bf16x8 a1 = *(const bf16x8*)(Wl + (wv * 32 + 16 + (lane & 15)) * 256 +
                                         (kkoff[kk] ^ axor));
            #pragma unroll
            for (int pf = 0; pf < 4; ++pf) {
                bf16x8 bv = *(const bf16x8*)(Xl + ubase[pf] + (kkoff[kk] ^ bswz[pf]));
                acc[0][pf] = __builtin_amdgcn_mfma_f32_16x16x32_bf16(a0, bv, acc[0][pf], 0, 0, 0);
                acc[1][pf] = __builtin_amdgcn_mfma_f32_16x16x32_bf16(a1, bv, acc[1][pf], 0, 0, 0);
            }
        }
    }

    const int pcol = lane & 15;
    const int rowq = lane >> 4;
    #pragma unroll
    for (int a = 0; a < 2; ++a) {
        int o0 = wv * 32 + a * 16 + rowq * 4;
        #pragma unroll
        for (int pf = 0; pf < 4; ++pf) {
            int p = pf * 16 + pcol;
            if (p < WW) {
                #pragma unroll
                for (int reg = 0; reg < 4; ++reg) {
                    out[(((size_t)b * OC + (o0 + reg)) * HH + h) * WW + p] = acc[a][pf][reg];
                }
            }
        }
    }
}

extern "C" void kernel_launch(void* const* d_in, const int* in_sizes, int n_in,
                              void* d_out, int out_size, void* d_ws, size_t ws_size,
                              hipStream_t stream) {
    const float* x  = (const float*)d_in[0];   // [32,128,56,56]
    const float* z  = (const float*)d_in[1];   // [32,512]
    const float* Wh = (const float*)d_in[2];   // [147456,512]
    const float* bh = (const float*)d_in[3];   // [147456]
    float* out = (float*)d_out;

    short* wbf = (short*)d_ws;                               // 9,437,184 B
    short* xt  = (short*)((char*)d_ws + (size_t)BB * NRS * OI * 2);  // +25,690,112 B

    head_kernel<<<dim3(WROWS / 128), 256, 0, stream>>>(Wh, z, bh, wbf);
    transpose_kernel<<<dim3(HH, BB), 256, 0, stream>>>(x, xt);
    conv_kernel<<<dim3(HH, BB), 256, 0, stream>>>(wbf, xt, out);
}

// Round 5
// 164.517 us; speedup vs baseline: 1.0725x; 1.0630x over previous
//
#include <hip/hip_runtime.h>
#include <hip/hip_bf16.h>
#include <stdint.h>

#define BB 32
#define IC 128
#define OC 128
#define HH 56
#define WW 56
#define ZD 512
#define NRS 9
#define OI (OC*IC)            // 16384
#define WROWS (OI*NRS)        // 147456
#define WDIM 58               // conv LDS width index u = w_in+1, 0..57

typedef float  f32x4  __attribute__((ext_vector_type(4)));
typedef short  bf16x8 __attribute__((ext_vector_type(8)));

static __device__ __forceinline__ short f2bf(float f) {
    uint32_t u = __float_as_uint(f);
    uint32_t r = (u + 0x7fffu + ((u >> 16) & 1u)) >> 16;
    return (short)r;
}
static __device__ __forceinline__ short f2bf_hw(float f) {
    __hip_bfloat16 h = __float2bfloat16(f);
    return *reinterpret_cast<short*>(&h);
}
static __device__ __forceinline__ float bf2f(short s) {
    uint32_t u = ((uint32_t)(uint16_t)s) << 16;
    return __uint_as_float(u);
}
static __device__ __forceinline__ void gll16(const void* g, void* l) {
    __builtin_amdgcn_global_load_lds(
        (const __attribute__((address_space(1))) uint32_t*)g,
        (__attribute__((address_space(3))) uint32_t*)l, 16, 0, 0);
}

// ---------------------------------------------------------------------------
// Kernel 1 (v5): head, DRAM-contiguous streaming + wave-private pipelines.
// 256 blocks (1/CU), 4 waves; wave owns 16-row groups, 9 groups/wave.
// Strip = 16 rows x 512 B (contiguous per row), 3 bufs/wave, 2-ahead prefetch,
// per-wave counted vmcnt, NO barriers in the main loop.
// Output: natural layout wnat[b][rowg] with 32-B-contiguous store segments.
// ---------------------------------------------------------------------------
__global__ __launch_bounds__(256) void head_kernel(
    const float* __restrict__ Wh, const float* __restrict__ z,
    short* __restrict__ wnat)
{
    __shared__ __align__(16) char Zl[32 * 1024];       // z bf16 swizzled, 32 KB
    __shared__ __align__(16) char Wl[4 * 3 * 8192];    // 4 waves x 3 bufs x 8 KB
    const int tid  = threadIdx.x;
    const int lane = tid & 63;
    const int wv   = tid >> 6;

    // stage z once: thread t -> b = t>>3, k-range (t&7)*64..+63, swz ^((b&7)<<4)
    {
        const int b = tid >> 3, ks = (tid & 7) * 64;
        const float* zp = z + (size_t)b * ZD + ks;
        const int bx = (b & 7) << 4;
        #pragma unroll
        for (int j8 = 0; j8 < 8; ++j8) {
            f32x4 v0 = *(const f32x4*)(zp + j8 * 8);
            f32x4 v1 = *(const f32x4*)(zp + j8 * 8 + 4);
            bf16x8 pk;
            pk[0] = f2bf_hw(v0.x); pk[1] = f2bf_hw(v0.y);
            pk[2] = f2bf_hw(v0.z); pk[3] = f2bf_hw(v0.w);
            pk[4] = f2bf_hw(v1.x); pk[5] = f2bf_hw(v1.y);
            pk[6] = f2bf_hw(v1.z); pk[7] = f2bf_hw(v1.w);
            *(bf16x8*)(Zl + b * 1024 + ((ks * 2 + j8 * 16) ^ bx)) = pk;
        }
    }
    __syncthreads();   // full drain: Zl ready, no VMEM outstanding

    const int rl = lane & 15;            // W-row within group (D col); b in A
    const int kq = lane >> 4;            // k-quadrant
    const int zxor = (rl & 7) << 4;
    const int q  = lane >> 5;            // row parity within staging pair

    // per-lane staging offsets: instr i covers rows {2i, 2i+1}, 512 B each,
    // source pre-swizzled so LDS holds (row, c ^ ((row&7)<<4)) linearly.
    uint32_t O[4];
    #pragma unroll
    for (int j = 0; j < 4; ++j)
        O[j] = j * 4096 + q * 2048 +
               (((lane & 31) * 16) ^ (((2 * j + q) & 7) << 4));

    const char* WB = (const char*)Wh +
        (size_t)(blockIdx.x * 576 + wv * 16) * (ZD * 4);
    char* WLb = Wl + wv * 24576;

    #define STAGE(gg, ss, buf)                                                  \
        {                                                                       \
            const char* sb_ = WB + (size_t)(gg) * 131072 + (ss) * 512;          \
            char* db_ = WLb + (buf) * 8192;                                     \
            _Pragma("unroll")                                                   \
            for (int i_ = 0; i_ < 8; ++i_)                                      \
                gll16(sb_ + (i_ >> 2) * 16384 + O[i_ & 3], db_ + i_ * 1024);    \
        }

    STAGE(0, 0, 0);
    STAGE(0, 1, 1);

    int bufc = 0;   // buffer of strip currently being computed
    for (int g = 0; g < 9; ++g) {
        f32x4 acc0 = {0.f, 0.f, 0.f, 0.f}, acc1 = {0.f, 0.f, 0.f, 0.f};
        #pragma unroll
        for (int s = 0; s < 4; ++s) {
            // counted waits (in-order retirement):
            //   steady: strips t..t+1 outstanding -> vmcnt(8)
            //   first strip after a store burst (8 stores): vmcnt(16)
            //   last strip of kernel: vmcnt(0)
            if (s == 0) {
                if (g) { asm volatile("s_waitcnt vmcnt(16)" ::: "memory"); }
                else   { asm volatile("s_waitcnt vmcnt(8)"  ::: "memory"); }
            } else if (s == 3) {
                if (g == 8) { asm volatile("s_waitcnt vmcnt(0)" ::: "memory"); }
                else        { asm volatile("s_waitcnt vmcnt(8)" ::: "memory"); }
            } else {
                asm volatile("s_waitcnt vmcnt(8)" ::: "memory");
            }
            __builtin_amdgcn_sched_barrier(0);

            const char* cb = WLb + bufc * 8192;
            #pragma unroll
            for (int j = 0; j < 4; ++j) {
                const int kb = s * 4 + j;
                const int koff = (kb * 64 + kq * 16) ^ zxor;
                bf16x8 a0 = *(const bf16x8*)(Zl + rl * 1024 + koff);
                bf16x8 a1 = *(const bf16x8*)(Zl + (16 + rl) * 1024 + koff);
                f32x4 lo = *(const f32x4*)(cb + rl * 512 + ((j * 128 + kq * 32) ^ zxor));
                f32x4 hi = *(const f32x4*)(cb + rl * 512 + ((j * 128 + kq * 32 + 16) ^ zxor));
                bf16x8 bw;
                bw[0] = f2bf_hw(lo.x); bw[1] = f2bf_hw(lo.y);
                bw[2] = f2bf_hw(lo.z); bw[3] = f2bf_hw(lo.w);
                bw[4] = f2bf_hw(hi.x); bw[5] = f2bf_hw(hi.y);
                bw[6] = f2bf_hw(hi.z); bw[7] = f2bf_hw(hi.w);
                acc0 = __builtin_amdgcn_mfma_f32_16x16x32_bf16(a0, bw, acc0, 0, 0, 0);
                acc1 = __builtin_amdgcn_mfma_f32_16x16x32_bf16(a1, bw, acc1, 0, 0, 0);
            }

            if (s == 3) {
                // group done: 8 coalesced-segment stores (4 x 32 B per instr)
                const int rowg = blockIdx.x * 576 + g * 64 + wv * 16 + rl;
                #pragma unroll
                for (int reg = 0; reg < 4; ++reg) {
                    const int b0 = kq * 4 + reg;
                    wnat[(size_t)b0 * WROWS + rowg]        = f2bf(acc0[reg]);
                    wnat[(size_t)(16 + b0) * WROWS + rowg] = f2bf(acc1[reg]);
                }
            }

            // issue strip u+2 (strip (g + (s>=2), (s+2)&3)), buffer (bufc+2)%3
            {
                const int su = 4 * g + s + 2;
                if (su < 36) {
                    const int sbuf = (bufc + 2) % 3;
                    const int gg = g + (s >= 2 ? 1 : 0);
                    const int ss = (s + 2) & 3;
                    STAGE(gg, ss, sbuf);
                }
            }
            bufc = (bufc == 2) ? 0 : bufc + 1;
        }
    }
    #undef STAGE
}

// ---------------------------------------------------------------------------
// Kernel 1b: repack wnat[b][rowg] -> wbf[b][rs][oi], adding bias.
// Thread owns 8 oi x 9 rs = 72 consecutive rowg; reads 9 x 16 B contiguous,
// writes 9 x 16 B (1 KB/wave contiguous per rs). In-register transpose.
// ---------------------------------------------------------------------------
__global__ __launch_bounds__(256) void repack_kernel(
    const short* __restrict__ wnat, const float* __restrict__ bh,
    short* __restrict__ wbf)
{
    const int b = blockIdx.y;
    const int oi0 = blockIdx.x * 2048 + threadIdx.x * 8;
    const short* src = wnat + (size_t)b * WROWS + (size_t)oi0 * 9;
    const float* bp  = bh + (size_t)oi0 * 9;

    bf16x8 in[9];
    #pragma unroll
    for (int j = 0; j < 9; ++j) in[j] = *(const bf16x8*)(src + j * 8);
    f32x4 bv[18];
    #pragma unroll
    for (int m = 0; m < 18; ++m) bv[m] = *(const f32x4*)(bp + m * 4);

    #pragma unroll
    for (int rs = 0; rs < 9; ++rs) {
        bf16x8 o;
        #pragma unroll
        for (int jj = 0; jj < 8; ++jj) {
            const int e = jj * 9 + rs;
            float v = bf2f(in[e >> 3][e & 7]) + bv[e >> 2][e & 3];
            o[jj] = f2bf(v);
        }
        *(bf16x8*)(wbf + ((size_t)(b * 9 + rs)) * OI + oi0) = o;
    }
}

// ---------------------------------------------------------------------------
// Kernel 2: x [b][i][h][w] fp32  ->  xt [b][h][w][i] bf16
// ---------------------------------------------------------------------------
__global__ __launch_bounds__(256) void transpose_kernel(
    const float* __restrict__ x, short* __restrict__ xt)
{
    const int h = blockIdx.x;          // 56
    const int b = blockIdx.y;          // 32
    const int w = threadIdx.x & 63;
    const int yq = threadIdx.x >> 6;   // 0..3
    if (w >= WW) return;
    const float* xp = x + (size_t)b * IC * HH * WW + h * WW + w;
    short* op = xt + (((size_t)(b * HH + h)) * WW + w) * IC;
    #pragma unroll
    for (int q = 0; q < 4; ++q) {
        int ic = yq * 4 + q;           // 0..15
        bf16x8 pk;
        #pragma unroll
        for (int j = 0; j < 8; ++j) {
            float v = xp[(size_t)(ic * 8 + j) * (HH * WW)];
            pk[j] = f2bf(v);
        }
        *(bf16x8*)(op + ic * 8) = pk;
    }
}

// ---------------------------------------------------------------------------
// Kernel 3: per-sample conv as 9 shifted GEMMs with bf16 MFMA (unchanged).
// ---------------------------------------------------------------------------
__global__ __launch_bounds__(256) void conv_kernel(
    const short* __restrict__ wbf,   // [b][rs][o][i] bf16
    const short* __restrict__ xt,    // [b][h][w][i]  bf16
    float* __restrict__ out)         // [b][o][h][w]  fp32
{
    __shared__ __align__(16) char Xl[3 * WDIM * 256];  // 44544 B
    __shared__ __align__(16) char Wl[128 * 256];       // 32768 B
    const int tid  = threadIdx.x;
    const int lane = tid & 63;
    const int wv   = tid >> 6;       // wave 0..3
    const int h = blockIdx.x;        // 56
    const int b = blockIdx.y;        // 32

    #pragma unroll
    for (int q = 0; q < 11; ++q) {
        int idx = tid + q * 256;
        if (idx < 3 * WDIM * 16) ((f32x4*)Xl)[idx] = (f32x4){0.f, 0.f, 0.f, 0.f};
    }
    __syncthreads();

    for (int r = 0; r < 3; ++r) {
        int hin = h + r - 1;
        if (hin < 0 || hin >= HH) continue;
        const char* src = (const char*)(xt + ((size_t)(b * HH + hin)) * WW * IC);
        char* dstbase = Xl + (r * WDIM + 1) * 256;
        for (int it = wv; it < 14; it += 4) {
            int c = it * 64 + lane;
            int u = r * WDIM + 1 + (c >> 4);
            int soff = (c * 16) ^ ((u & 7) << 4);
            gll16(src + soff, dstbase + it * 1024);
        }
    }

    f32x4 acc[2][4];
    #pragma unroll
    for (int a = 0; a < 2; ++a)
        #pragma unroll
        for (int p = 0; p < 4; ++p) acc[a][p] = (f32x4){0.f, 0.f, 0.f, 0.f};

    const int axor = (lane & 7) << 4;
    int kkoff[4];
    #pragma unroll
    for (int kk = 0; kk < 4; ++kk) kkoff[kk] = kk * 64 + ((lane >> 4) << 4);

    for (int rs = 0; rs < 9; ++rs) {
        __syncthreads();
        const char* wsrc = (const char*)(wbf + ((size_t)b * NRS + rs) * OI);
        for (int it = wv; it < 32; it += 4) {
            int c = it * 64 + lane;
            int soff = (c * 16) ^ (((c >> 4) & 7) << 4);
            gll16(wsrc + soff, Wl + it * 1024);
        }
        __syncthreads();

        const int r = rs / 3, s = rs - 3 * (rs / 3);
        int ubase[4], bswz[4];
        #pragma unroll
        for (int pf = 0; pf < 4; ++pf) {
            int p = pf * 16 + (lane & 15);
            int pc = p > 55 ? 55 : p;
            int uu = r * WDIM + pc + s;
            ubase[pf] = uu * 256;
            bswz[pf] = (uu & 7) << 4;
        }
        #pragma unroll
        for (int kk = 0; kk < 4; ++kk) {
            bf16x8 a0 = *(const bf16x8*)(Wl + (wv * 32 + (lane & 15)) * 256 +
                                         (kkoff[kk] ^ axor));
            bf16x8 a1 = *(const bf16x8*)(Wl + (wv * 32 + 16 + (lane & 15)) * 256 +
                                         (kkoff[kk] ^ axor));
            #pragma unroll
            for (int pf = 0; pf < 4; ++pf) {
                bf16x8 bv = *(const bf16x8*)(Xl + ubase[pf] + (kkoff[kk] ^ bswz[pf]));
                acc[0][pf] = __builtin_amdgcn_mfma_f32_16x16x32_bf16(a0, bv, acc[0][pf], 0, 0, 0);
                acc[1][pf] = __builtin_amdgcn_mfma_f32_16x16x32_bf16(a1, bv, acc[1][pf], 0, 0, 0);
            }
        }
    }

    const int pcol = lane & 15;
    const int rowq = lane >> 4;
    #pragma unroll
    for (int a = 0; a < 2; ++a) {
        int o0 = wv * 32 + a * 16 + rowq * 4;
        #pragma unroll
        for (int pf = 0; pf < 4; ++pf) {
            int p = pf * 16 + pcol;
            if (p < WW) {
                #pragma unroll
                for (int reg = 0; reg < 4; ++reg) {
                    out[(((size_t)b * OC + (o0 + reg)) * HH + h) * WW + p] = acc[a][pf][reg];
                }
            }
        }
    }
}

extern "C" void kernel_launch(void* const* d_in, const int* in_sizes, int n_in,
                              void* d_out, int out_size, void* d_ws, size_t ws_size,
                              hipStream_t stream) {
    const float* x  = (const float*)d_in[0];   // [32,128,56,56]
    const float* z  = (const float*)d_in[1];   // [32,512]
    const float* Wh = (const float*)d_in[2];   // [147456,512]
    const float* bh = (const float*)d_in[3];   // [147456]
    float* out = (float*)d_out;

    short* wnat = (short*)d_ws;                                  // 9,437,184 B
    short* wbf  = (short*)((char*)d_ws + 9437184);               // 9,437,184 B
    short* xt   = (short*)((char*)d_ws + 18874368);              // 25,690,112 B

    head_kernel<<<dim3(256), 256, 0, stream>>>(Wh, z, wnat);
    repack_kernel<<<dim3(8, 32), 256, 0, stream>>>(wnat, bh, wbf);
    transpose_kernel<<<dim3(HH, BB), 256, 0, stream>>>(x, xt);
    conv_kernel<<<dim3(HH, BB), 256, 0, stream>>>(wbf, xt, out);
}